// Round 2
// baseline (374.242 us; speedup 1.0000x reference)
//
#include <hip/hip_runtime.h>
#include <hip/hip_bf16.h>

// DeepSeek V4 MLA sparse attention, MI355X gfx950.
#define T_TOK 512
#define NH    64
#define HD    576
#define DVAL  512
#define NKV   8192
#define TOPK  1024
#define KT    32
#define NITER (TOPK / KT)   // 32
#define KSTEPS (HD / 32)    // 18
#define SCALE 0.041666666666666664f  // 1/24

typedef __attribute__((ext_vector_type(4))) float f32x4;
typedef __attribute__((ext_vector_type(8))) _Float16 half8;
typedef __attribute__((ext_vector_type(4))) unsigned short us4;
typedef __attribute__((ext_vector_type(8))) unsigned short us8;
typedef __attribute__((ext_vector_type(4))) int i32x4;

__device__ __forceinline__ unsigned short f2h(float x) {
    _Float16 h = (_Float16)x;
    return __builtin_bit_cast(unsigned short, h);
}
// reductions over the 16 lanes of a quad (xor masks < 16 stay in-quad)
__device__ __forceinline__ float rmax16(float x) {
    x = fmaxf(x, __shfl_xor(x, 1));
    x = fmaxf(x, __shfl_xor(x, 2));
    x = fmaxf(x, __shfl_xor(x, 4));
    x = fmaxf(x, __shfl_xor(x, 8));
    return x;
}
__device__ __forceinline__ float rsum16(float x) {
    x += __shfl_xor(x, 1);
    x += __shfl_xor(x, 2);
    x += __shfl_xor(x, 4);
    x += __shfl_xor(x, 8);
    return x;
}

// ---- prep: kv fp32 -> fp16 in workspace (9.4 MB) ----
__global__ void cvt_kv_f16(const float* __restrict__ kv, unsigned short* __restrict__ kvb) {
    int i = blockIdx.x * 256 + threadIdx.x;          // covers NKV*HD/8 exactly
    const f32x4* src = (const f32x4*)kv + (size_t)i * 2;
    f32x4 a = src[0];
    f32x4 b = src[1];
    us8 w;
    w[0]=f2h(a[0]); w[1]=f2h(a[1]); w[2]=f2h(a[2]); w[3]=f2h(a[3]);
    w[4]=f2h(b[0]); w[5]=f2h(b[1]); w[6]=f2h(b[2]); w[7]=f2h(b[3]);
    ((us8*)kvb)[i] = w;
}

#define G_LD  584   // 576 + 8 fp16 pad (row 1168 B, 16B-mult, 292 dw ≡ 4 mod 32)
#define GT_LD 40    // 32 + 8 pad (row 80 B, 16B-mult); columns XOR-swizzled by (row>>3)&3
#define P_LD  40

__global__ __launch_bounds__(512, 2) void mla_sparse_kernel(
    const float* __restrict__ q, const int* __restrict__ topk,
    const float* __restrict__ sink, const unsigned short* __restrict__ kvb,
    float* __restrict__ out)
{
    __shared__ unsigned short g[KT][G_LD];     // gathered tile [key][d]     37,376 B
    __shared__ unsigned short gt[DVAL][GT_LD]; // transposed [vcol][key]     40,960 B
    __shared__ unsigned short pbuf[NH][P_LD];  // P fp16 (per-wave-max scaled) 5,120 B
    __shared__ float bias[KT];
    __shared__ float mrun[2][NH], lrun[2][NH]; // parity double-buffered running stats
    __shared__ float mpart[2][NH], spart[2][NH]; // per key-half partial max/sum
    // total ~85.6 KB -> 1 block/CU

    const int t    = blockIdx.x;
    const int tid  = threadIdx.x;
    const int wave = tid >> 6;
    const int lane = tid & 63;
    const int quad = lane >> 4;
    const int l16  = lane & 15;
    const int mtile = wave & 3;
    const int ntile = wave >> 2;
    const int col0  = wave * 64;

    // sink folded into online-softmax init: m = sink[h], l = exp(sink-m) = 1
    if (tid < NH) { mrun[0][tid] = sink[tid]; lrun[0][tid] = 1.0f; }

    // Q A-frags in registers (72 VGPRs)
    half8 qf[KSTEPS];
    {
        const float* qrow = q + ((size_t)t * NH + (mtile * 16 + l16)) * HD;
        #pragma unroll
        for (int ks = 0; ks < KSTEPS; ks++) {
            int d0 = ks * 32 + quad * 8;
            f32x4 a = *(const f32x4*)(qrow + d0);
            f32x4 b = *(const f32x4*)(qrow + d0 + 4);
            half8 h;
            h[0]=(_Float16)a[0]; h[1]=(_Float16)a[1]; h[2]=(_Float16)a[2]; h[3]=(_Float16)a[3];
            h[4]=(_Float16)b[0]; h[5]=(_Float16)b[1]; h[6]=(_Float16)b[2]; h[7]=(_Float16)b[3];
            qf[ks] = h;
        }
    }

    f32x4 acc[4][4];
    const f32x4 zero = {0.f, 0.f, 0.f, 0.f};
    #pragma unroll
    for (int mt = 0; mt < 4; mt++)
        #pragma unroll
        for (int nt = 0; nt < 4; nt++) acc[mt][nt] = zero;

    const int* tkrow = topk + (size_t)t * TOPK;
    // staging geometry
    const int kgA  = tid >> 7;            // 8-key group 0..3
    const int d0A  = (tid & 127) * 4;     // value dims 0..508
    const int cswz = ((tid & 127) >> 1) & 3; // gt column swizzle = (row>>3)&3, row=4*(tid&127)+dd
    const int keyB = tid >> 4;            // rope part: 1 us4 per thread
    const int dB   = 512 + (tid & 15) * 4;

    // prefetch registers (gather for next iteration)
    us4 v0, v1, v2, v3, v4, v5, v6, v7, wB;
    int nb;

    auto prefetch = [&](int pit) {
        const int* ip = tkrow + pit * KT + kgA * 8;
        i32x4 ra = *(const i32x4*)ip;
        i32x4 rb = *(const i32x4*)(ip + 4);
        int r0 = ra[0] < 0 ? 0 : ra[0];
        int r1 = ra[1] < 0 ? 0 : ra[1];
        int r2 = ra[2] < 0 ? 0 : ra[2];
        int r3 = ra[3] < 0 ? 0 : ra[3];
        int r4 = rb[0] < 0 ? 0 : rb[0];
        int r5 = rb[1] < 0 ? 0 : rb[1];
        int r6 = rb[2] < 0 ? 0 : rb[2];
        int r7 = rb[3] < 0 ? 0 : rb[3];
        v0 = *(const us4*)(kvb + (size_t)r0 * HD + d0A);
        v1 = *(const us4*)(kvb + (size_t)r1 * HD + d0A);
        v2 = *(const us4*)(kvb + (size_t)r2 * HD + d0A);
        v3 = *(const us4*)(kvb + (size_t)r3 * HD + d0A);
        v4 = *(const us4*)(kvb + (size_t)r4 * HD + d0A);
        v5 = *(const us4*)(kvb + (size_t)r5 * HD + d0A);
        v6 = *(const us4*)(kvb + (size_t)r6 * HD + d0A);
        v7 = *(const us4*)(kvb + (size_t)r7 * HD + d0A);
        int ib = tkrow[pit * KT + keyB];
        int rB = ib < 0 ? 0 : ib;
        wB = *(const us4*)(kvb + (size_t)rB * HD + dB);
        nb = tkrow[pit * KT + (tid & (KT - 1))];
    };

    prefetch(0);

    for (int it = 0; it < NITER; it++) {
        const int p = it & 1;
        // ---- stage prefetched registers into LDS ----
        {
            *(us4*)&g[kgA * 8 + 0][d0A] = v0;
            *(us4*)&g[kgA * 8 + 1][d0A] = v1;
            *(us4*)&g[kgA * 8 + 2][d0A] = v2;
            *(us4*)&g[kgA * 8 + 3][d0A] = v3;
            *(us4*)&g[kgA * 8 + 4][d0A] = v4;
            *(us4*)&g[kgA * 8 + 5][d0A] = v5;
            *(us4*)&g[kgA * 8 + 6][d0A] = v6;
            *(us4*)&g[kgA * 8 + 7][d0A] = v7;
            #pragma unroll
            for (int dd = 0; dd < 4; dd++) {     // 8-key packs -> swizzled b128 writes
                us8 w;
                w[0]=v0[dd]; w[1]=v1[dd]; w[2]=v2[dd]; w[3]=v3[dd];
                w[4]=v4[dd]; w[5]=v5[dd]; w[6]=v6[dd]; w[7]=v7[dd];
                *(us8*)&gt[d0A + dd][((kgA ^ cswz) & 3) * 8] = w;
            }
            *(us4*)&g[keyB][dB] = wB;
            if (tid < KT) bias[tid] = (nb < 0) ? -__builtin_inff() : 0.0f;
        }
        __syncthreads();

        if (it + 1 < NITER) prefetch(it + 1);   // latency hides under S+softmax+PV

        // ---- S = Q * G^T (one 16x16 tile per wave) + in-register softmax ----
        {
            f32x4 sacc = zero;
            #pragma unroll
            for (int ks = 0; ks < KSTEPS; ks++) {
                half8 bf = *(const half8*)&g[ntile * 16 + l16][ks * 32 + quad * 8];
                sacc = __builtin_amdgcn_mfma_f32_16x16x32_f16(qf[ks], bf, sacc, 0, 0, 0);
            }
            float bb = bias[ntile * 16 + l16];
            float s0 = sacc[0] * SCALE + bb;
            float s1 = sacc[1] * SCALE + bb;
            float s2 = sacc[2] * SCALE + bb;
            float s3 = sacc[3] * SCALE + bb;
            float m0 = fmaxf(rmax16(s0), -1e30f);
            float m1 = fmaxf(rmax16(s1), -1e30f);
            float m2 = fmaxf(rmax16(s2), -1e30f);
            float m3 = fmaxf(rmax16(s3), -1e30f);
            float p0 = __expf(s0 - m0);
            float p1 = __expf(s1 - m1);
            float p2 = __expf(s2 - m2);
            float p3 = __expf(s3 - m3);
            float sm0 = rsum16(p0);
            float sm1 = rsum16(p1);
            float sm2 = rsum16(p2);
            float sm3 = rsum16(p3);
            int kk = ntile * 16 + l16;
            int hb = mtile * 16 + quad * 4;
            pbuf[hb + 0][kk] = f2h(p0);
            pbuf[hb + 1][kk] = f2h(p1);
            pbuf[hb + 2][kk] = f2h(p2);
            pbuf[hb + 3][kk] = f2h(p3);
            if (l16 < 4) {
                float mv = l16 == 0 ? m0 : l16 == 1 ? m1 : l16 == 2 ? m2 : m3;
                float sv = l16 == 0 ? sm0 : l16 == 1 ? sm1 : l16 == 2 ? sm2 : sm3;
                mpart[ntile][hb + l16] = mv;
                spart[ntile][hb + l16] = sv;
            }
        }
        __syncthreads();

        // ---- combine (canonical, wave 0) + per-wave scale recompute + PV ----
        if (tid < NH) {
            int h = tid;
            float mo = mrun[p][h];
            float ma = mpart[0][h];
            float mbv = mpart[1][h];
            float mn = fmaxf(fmaxf(mo, ma), mbv);
            mrun[1 - p][h] = mn;
            lrun[1 - p][h] = lrun[p][h] * __expf(mo - mn)
                           + spart[0][h] * __expf(ma - mn)
                           + spart[1][h] * __expf(mbv - mn);
        }
        {
            half8 pa[4];
            f32x4 al4[4];
            #pragma unroll
            for (int mt = 0; mt < 4; mt++) {
                // A-frag scale: head = mt*16+l16, key-half = quad>>1
                int hA = mt * 16 + l16;
                float moA = mrun[p][hA];
                float mA0 = mpart[0][hA];
                float mA1 = mpart[1][hA];
                float mnA = fmaxf(fmaxf(moA, mA0), mA1);
                float sh = __expf((quad < 2 ? mA0 : mA1) - mnA);
                half8 t8 = *(const half8*)&pbuf[hA][quad * 8];
                pa[mt] = t8 * (_Float16)sh;
                // accumulator rescale alphas for C-rows mt*16+quad*4+r
                int hC = mt * 16 + quad * 4;
                f32x4 moC = *(const f32x4*)&mrun[p][hC];
                f32x4 mC0 = *(const f32x4*)&mpart[0][hC];
                f32x4 mC1 = *(const f32x4*)&mpart[1][hC];
                f32x4 al;
                al[0] = __expf(moC[0] - fmaxf(fmaxf(moC[0], mC0[0]), mC1[0]));
                al[1] = __expf(moC[1] - fmaxf(fmaxf(moC[1], mC0[1]), mC1[1]));
                al[2] = __expf(moC[2] - fmaxf(fmaxf(moC[2], mC0[2]), mC1[2]));
                al[3] = __expf(moC[3] - fmaxf(fmaxf(moC[3], mC0[3]), mC1[3]));
                al4[mt] = al;
            }
            half8 vb[4];
            #pragma unroll
            for (int nt = 0; nt < 4; nt++) {
                int r = col0 + nt * 16 + l16;
                int cc = ((quad ^ (r >> 3)) & 3) * 8;   // undo storage swizzle
                vb[nt] = *(const half8*)&gt[r][cc];
            }
            #pragma unroll
            for (int mt = 0; mt < 4; mt++) {
                #pragma unroll
                for (int nt = 0; nt < 4; nt++) {
                    acc[mt][nt] *= al4[mt];
                    acc[mt][nt] = __builtin_amdgcn_mfma_f32_16x16x32_f16(pa[mt], vb[nt], acc[mt][nt], 0, 0, 0);
                }
            }
        }
        __syncthreads();  // g/gt/pbuf/mpart free for next iteration
    }

    // ---- epilogue: divide by final denom (parity 0 after 32 iters), store ----
    #pragma unroll
    for (int mt = 0; mt < 4; mt++) {
        f32x4 lv = *(const f32x4*)&lrun[0][mt * 16 + quad * 4];
        f32x4 linv;
        linv[0] = 1.0f / lv[0]; linv[1] = 1.0f / lv[1];
        linv[2] = 1.0f / lv[2]; linv[3] = 1.0f / lv[3];
        #pragma unroll
        for (int nt = 0; nt < 4; nt++) {
            int vcol = col0 + nt * 16 + l16;
            f32x4 r = acc[mt][nt] * linv;
            #pragma unroll
            for (int rr = 0; rr < 4; rr++) {
                int head = mt * 16 + quad * 4 + rr;
                out[((size_t)t * NH + head) * DVAL + vcol] = r[rr];
            }
        }
    }
}

extern "C" void kernel_launch(void* const* d_in, const int* in_sizes, int n_in,
                              void* d_out, int out_size, void* d_ws, size_t ws_size,
                              hipStream_t stream) {
    const float* q    = (const float*)d_in[0];   // [512,64,576]
    const float* kv   = (const float*)d_in[1];   // [8192,576]
    const int*   topk = (const int*)d_in[2];     // [512,1024]
    const float* sink = (const float*)d_in[3];   // [64]
    float* out = (float*)d_out;                  // [512,64,512]
    unsigned short* kvb = (unsigned short*)d_ws; // fp16 kv cache, 9,437,184 B

    cvt_kv_f16<<<NKV * HD / (256 * 8), 256, 0, stream>>>(kv, kvb);
    mla_sparse_kernel<<<T_TOK, 512, 0, stream>>>(q, topk, sink, kvb, out);
}

// Round 3
// 369.728 us; speedup vs baseline: 1.0122x; 1.0122x over previous
//
#include <hip/hip_runtime.h>
#include <hip/hip_bf16.h>

// DeepSeek V4 MLA sparse attention, MI355X gfx950.
// R3: 256-thread blocks (1 token each), 2 blocks/CU for independent barrier
// domains; in-place fp16 softmax in pbuf (no sbuf); per-lane running stats.
#define T_TOK 512
#define NH    64
#define HD    576
#define DVAL  512
#define NKV   8192
#define TOPK  1024
#define KT    32
#define NITER (TOPK / KT)   // 32
#define KSTEPS (HD / 32)    // 18
#define SCALE 0.041666666666666664f  // 1/24

typedef __attribute__((ext_vector_type(4))) float f32x4;
typedef __attribute__((ext_vector_type(8))) _Float16 half8;
typedef __attribute__((ext_vector_type(4))) unsigned short us4;
typedef __attribute__((ext_vector_type(8))) unsigned short us8;
typedef __attribute__((ext_vector_type(4))) int i32x4;

__device__ __forceinline__ unsigned short f2h(float x) {
    _Float16 h = (_Float16)x;
    return __builtin_bit_cast(unsigned short, h);
}
__device__ __forceinline__ float h2f(unsigned short u) {
    return (float)__builtin_bit_cast(_Float16, u);
}

// ---- prep: kv fp32 -> fp16 in workspace (9.4 MB) ----
__global__ void cvt_kv_f16(const float* __restrict__ kv, unsigned short* __restrict__ kvb) {
    int i = blockIdx.x * 256 + threadIdx.x;          // covers NKV*HD/8 exactly
    const f32x4* src = (const f32x4*)kv + (size_t)i * 2;
    f32x4 a = src[0];
    f32x4 b = src[1];
    us8 w;
    w[0]=f2h(a[0]); w[1]=f2h(a[1]); w[2]=f2h(a[2]); w[3]=f2h(a[3]);
    w[4]=f2h(b[0]); w[5]=f2h(b[1]); w[6]=f2h(b[2]); w[7]=f2h(b[3]);
    ((us8*)kvb)[i] = w;
}

#define G_LD  584   // 576 + 8 pad (row 1168 B, 16B-mult, stride 292 dw ≡ 4 mod 32)
#define GT_LD 36    // 32 + 4 pad (row 72 B, 8B-mult); octets XOR-swizzled by (row>>3)&3
#define P_LD  40    // 32 + 8 pad (row 80 B, 16B-mult)

__global__ __launch_bounds__(256, 2) void mla_sparse_kernel(
    const float* __restrict__ q, const int* __restrict__ topk,
    const float* __restrict__ sink, const unsigned short* __restrict__ kvb,
    float* __restrict__ out)
{
    __shared__ unsigned short g[KT][G_LD];     // gathered tile [key][d]   37,376 B
    __shared__ unsigned short gt[DVAL][GT_LD]; // transposed [vcol][key]   36,864 B
    __shared__ unsigned short pbuf[NH][P_LD];  // scores, softmaxed IN PLACE 5,120 B
    __shared__ float bias[KT];                 //                             128 B
    __shared__ float alphaL[NH];               // per-iter rescale            256 B
    __shared__ float lrunL[NH];                // final denom (epilogue)      256 B
    // total 80,000 B -> 2 blocks/CU

    const int t    = blockIdx.x;
    const int tid  = threadIdx.x;
    const int wave = tid >> 6;      // 0..3 = S mtile
    const int lane = tid & 63;
    const int quad = lane >> 4;
    const int l16  = lane & 15;

    // softmax ownership: 4 lanes per head, private running stats in registers
    const int sm_h = tid >> 2;      // head 0..63
    const int sm_j = tid & 3;       // key-octet j*8..j*8+7
    float m_run = sink[sm_h];       // sink folded in: m=sink, l=exp(sink-m)=1
    float l_run = 1.0f;

    // Q A-frags in registers (72 VGPRs): wave's heads = wave*16 + l16
    half8 qf[KSTEPS];
    {
        const float* qrow = q + ((size_t)t * NH + (wave * 16 + l16)) * HD;
        #pragma unroll
        for (int ks = 0; ks < KSTEPS; ks++) {
            int d0 = ks * 32 + quad * 8;
            f32x4 a = *(const f32x4*)(qrow + d0);
            f32x4 b = *(const f32x4*)(qrow + d0 + 4);
            half8 h;
            h[0]=(_Float16)a[0]; h[1]=(_Float16)a[1]; h[2]=(_Float16)a[2]; h[3]=(_Float16)a[3];
            h[4]=(_Float16)b[0]; h[5]=(_Float16)b[1]; h[6]=(_Float16)b[2]; h[7]=(_Float16)b[3];
            qf[ks] = h;
        }
    }

    // PV: wave owns vcols [wave*128, +128): 4 mtiles x 8 ntiles
    f32x4 acc[4][8];
    const f32x4 zero = {0.f, 0.f, 0.f, 0.f};
    #pragma unroll
    for (int mt = 0; mt < 4; mt++)
        #pragma unroll
        for (int nt = 0; nt < 8; nt++) acc[mt][nt] = zero;

    const int col0 = wave * 128;
    const int* tkrow = topk + (size_t)t * TOPK;
    // staging geometry: value dims in 2 passes x 2 half-octets
    const int kgA = tid >> 6;            // key octet 0..3 (== wave)
    const int dcA = tid & 63;            // dim group
    const int keyB = tid >> 3;           // rope: key 0..31
    const int dB   = 512 + (tid & 7) * 8;

    for (int it = 0; it < NITER; it++) {
        // ---- staging: gather 32 fp16 rows into g and transposed gt ----
        {
            const int* ip = tkrow + it * KT + kgA * 8;
            i32x4 ra = *(const i32x4*)ip;
            i32x4 rb = *(const i32x4*)(ip + 4);
            unsigned int ro[8];
            ro[0] = (unsigned)(ra[0] < 0 ? 0 : ra[0]) * HD;
            ro[1] = (unsigned)(ra[1] < 0 ? 0 : ra[1]) * HD;
            ro[2] = (unsigned)(ra[2] < 0 ? 0 : ra[2]) * HD;
            ro[3] = (unsigned)(ra[3] < 0 ? 0 : ra[3]) * HD;
            ro[4] = (unsigned)(rb[0] < 0 ? 0 : rb[0]) * HD;
            ro[5] = (unsigned)(rb[1] < 0 ? 0 : rb[1]) * HD;
            ro[6] = (unsigned)(rb[2] < 0 ? 0 : rb[2]) * HD;
            ro[7] = (unsigned)(rb[3] < 0 ? 0 : rb[3]) * HD;
            #pragma unroll
            for (int c = 0; c < 2; c++) {
                int d0 = dcA * 4 + c * 256;
                #pragma unroll
                for (int jh = 0; jh < 2; jh++) {     // half-octets: 4 keys at a time
                    us4 v0 = *(const us4*)(kvb + ro[jh*4+0] + d0);
                    us4 v1 = *(const us4*)(kvb + ro[jh*4+1] + d0);
                    us4 v2 = *(const us4*)(kvb + ro[jh*4+2] + d0);
                    us4 v3 = *(const us4*)(kvb + ro[jh*4+3] + d0);
                    *(us4*)&g[kgA * 8 + jh*4 + 0][d0] = v0;
                    *(us4*)&g[kgA * 8 + jh*4 + 1][d0] = v1;
                    *(us4*)&g[kgA * 8 + jh*4 + 2][d0] = v2;
                    *(us4*)&g[kgA * 8 + jh*4 + 3][d0] = v3;
                    #pragma unroll
                    for (int dd = 0; dd < 4; dd++) {
                        us4 w;
                        w[0]=v0[dd]; w[1]=v1[dd]; w[2]=v2[dd]; w[3]=v3[dd];
                        int r = d0 + dd;
                        *(us4*)&gt[r][(((kgA ^ (r >> 3)) & 3) * 8) + jh * 4] = w;
                    }
                }
            }
            // rope dims 512..575 (g only)
            int ib = tkrow[it * KT + keyB];
            unsigned rB = (unsigned)(ib < 0 ? 0 : ib) * HD;
            *(us8*)&g[keyB][dB] = *(const us8*)(kvb + rB + dB);
            if (tid < KT) {
                int raw = tkrow[it * KT + tid];
                bias[tid] = raw < 0 ? -__builtin_inff() : 0.0f;
            }
        }
        __syncthreads();

        // ---- S = Q * G^T : wave computes 2 tiles (mtile=wave, ntile 0,1) ----
        {
            f32x4 s0 = zero, s1 = zero;
            #pragma unroll
            for (int ks = 0; ks < KSTEPS; ks++) {
                half8 b0 = *(const half8*)&g[l16][ks * 32 + quad * 8];
                half8 b1 = *(const half8*)&g[16 + l16][ks * 32 + quad * 8];
                s0 = __builtin_amdgcn_mfma_f32_16x16x32_f16(qf[ks], b0, s0, 0, 0, 0);
                s1 = __builtin_amdgcn_mfma_f32_16x16x32_f16(qf[ks], b1, s1, 0, 0, 0);
            }
            float b0 = bias[l16];
            float b1 = bias[16 + l16];
            int hb = wave * 16 + quad * 4;            // C-layout: row = quad*4+reg
            #pragma unroll
            for (int r = 0; r < 4; r++) {
                pbuf[hb + r][l16]      = f2h(s0[r] * SCALE + b0);
                pbuf[hb + r][16 + l16] = f2h(s1[r] * SCALE + b1);
            }
        }
        __syncthreads();

        // ---- softmax IN PLACE: 4 lanes/head, 8 keys each; stats in regs ----
        {
            us8 sv = *(const us8*)&pbuf[sm_h][sm_j * 8];
            float s0 = h2f(sv[0]), s1 = h2f(sv[1]), s2 = h2f(sv[2]), s3 = h2f(sv[3]);
            float s4 = h2f(sv[4]), s5 = h2f(sv[5]), s6 = h2f(sv[6]), s7 = h2f(sv[7]);
            float tm = fmaxf(fmaxf(fmaxf(s0, s1), fmaxf(s2, s3)),
                             fmaxf(fmaxf(s4, s5), fmaxf(s6, s7)));
            tm = fmaxf(tm, __shfl_xor(tm, 1));
            tm = fmaxf(tm, __shfl_xor(tm, 2));
            float m_new = fmaxf(m_run, tm);           // >= sink: finite
            float alpha = __expf(m_run - m_new);
            float p0 = __expf(s0 - m_new), p1 = __expf(s1 - m_new);
            float p2 = __expf(s2 - m_new), p3 = __expf(s3 - m_new);
            float p4 = __expf(s4 - m_new), p5 = __expf(s5 - m_new);
            float p6 = __expf(s6 - m_new), p7 = __expf(s7 - m_new);
            float ps = ((p0 + p1) + (p2 + p3)) + ((p4 + p5) + (p6 + p7));
            ps += __shfl_xor(ps, 1);
            ps += __shfl_xor(ps, 2);
            m_run = m_new;
            l_run = l_run * alpha + ps;
            us8 pw;
            pw[0]=f2h(p0); pw[1]=f2h(p1); pw[2]=f2h(p2); pw[3]=f2h(p3);
            pw[4]=f2h(p4); pw[5]=f2h(p5); pw[6]=f2h(p6); pw[7]=f2h(p7);
            *(us8*)&pbuf[sm_h][sm_j * 8] = pw;        // safe: own bytes only
            if (sm_j == 0) alphaL[sm_h] = alpha;
        }
        __syncthreads();

        // ---- PV: rescale acc by alpha, accumulate P * Gv ----
        {
            half8 pa[4];
            #pragma unroll
            for (int mt = 0; mt < 4; mt++) {
                pa[mt] = *(const half8*)&pbuf[mt * 16 + l16][quad * 8];
                f32x4 al = *(const f32x4*)&alphaL[mt * 16 + quad * 4];
                #pragma unroll
                for (int nt = 0; nt < 8; nt++) acc[mt][nt] *= al;
            }
            #pragma unroll
            for (int nt = 0; nt < 8; nt++) {
                int rr = col0 + nt * 16 + l16;
                us8 u = *(const us8*)&gt[rr][((quad ^ (rr >> 3)) & 3) * 8];
                half8 vb = __builtin_bit_cast(half8, u);
                #pragma unroll
                for (int mt = 0; mt < 4; mt++)
                    acc[mt][nt] = __builtin_amdgcn_mfma_f32_16x16x32_f16(pa[mt], vb, acc[mt][nt], 0, 0, 0);
            }
        }
        __syncthreads();  // g/gt/pbuf free for next staging
    }

    // publish final denominators, then epilogue
    if (sm_j == 0) lrunL[sm_h] = l_run;
    __syncthreads();

    #pragma unroll
    for (int mt = 0; mt < 4; mt++) {
        f32x4 lv = *(const f32x4*)&lrunL[mt * 16 + quad * 4];
        f32x4 linv;
        linv[0] = 1.0f / lv[0]; linv[1] = 1.0f / lv[1];
        linv[2] = 1.0f / lv[2]; linv[3] = 1.0f / lv[3];
        #pragma unroll
        for (int nt = 0; nt < 8; nt++) {
            int vcol = col0 + nt * 16 + l16;
            f32x4 r = acc[mt][nt] * linv;
            #pragma unroll
            for (int rr = 0; rr < 4; rr++) {
                int head = mt * 16 + quad * 4 + rr;
                out[((size_t)t * NH + head) * DVAL + vcol] = r[rr];
            }
        }
    }
}

extern "C" void kernel_launch(void* const* d_in, const int* in_sizes, int n_in,
                              void* d_out, int out_size, void* d_ws, size_t ws_size,
                              hipStream_t stream) {
    const float* q    = (const float*)d_in[0];   // [512,64,576]
    const float* kv   = (const float*)d_in[1];   // [8192,576]
    const int*   topk = (const int*)d_in[2];     // [512,1024]
    const float* sink = (const float*)d_in[3];   // [64]
    float* out = (float*)d_out;                  // [512,64,512]
    unsigned short* kvb = (unsigned short*)d_ws; // fp16 kv cache, 9,437,184 B

    cvt_kv_f16<<<NKV * HD / (256 * 8), 256, 0, stream>>>(kv, kvb);
    mla_sparse_kernel<<<T_TOK, 256, 0, stream>>>(q, topk, sink, kvb, out);
}

// Round 4
// 364.411 us; speedup vs baseline: 1.0270x; 1.0146x over previous
//
#include <hip/hip_runtime.h>
#include <hip/hip_bf16.h>

// DeepSeek V4 MLA sparse attention, MI355X gfx950.
// R4: single 512-thread block per token; wave-pair owns 16 heads with
// REDUNDANT S compute -> fully wave-local softmax (register stats, DPP
// shuffles); software-pipelined gather (regs in flight across compute);
// g single-buffered, gt/bias double-buffered; 2 barriers/iter (was 4).
#define T_TOK 512
#define NH    64
#define HD    576
#define DVAL  512
#define NKV   8192
#define TOPK  1024
#define KT    32
#define NITER (TOPK / KT)   // 32
#define KSTEPS (HD / 32)    // 18
#define SCALE 0.041666666666666664f  // 1/24

typedef __attribute__((ext_vector_type(4))) float f32x4;
typedef __attribute__((ext_vector_type(8))) _Float16 half8;
typedef __attribute__((ext_vector_type(4))) unsigned short us4;
typedef __attribute__((ext_vector_type(8))) unsigned short us8;
typedef __attribute__((ext_vector_type(4))) int i32x4;

__device__ __forceinline__ unsigned short f2h(float x) {
    _Float16 h = (_Float16)x;
    return __builtin_bit_cast(unsigned short, h);
}

// ---- prep: kv fp32 -> fp16 in workspace (9.4 MB) ----
__global__ void cvt_kv_f16(const float* __restrict__ kv, unsigned short* __restrict__ kvb) {
    int i = blockIdx.x * 256 + threadIdx.x;          // covers NKV*HD/8 exactly
    const f32x4* src = (const f32x4*)kv + (size_t)i * 2;
    f32x4 a = src[0];
    f32x4 b = src[1];
    us8 w;
    w[0]=f2h(a[0]); w[1]=f2h(a[1]); w[2]=f2h(a[2]); w[3]=f2h(a[3]);
    w[4]=f2h(b[0]); w[5]=f2h(b[1]); w[6]=f2h(b[2]); w[7]=f2h(b[3]);
    ((us8*)kvb)[i] = w;
}

#define G_LD  584   // 576+8 pad: row 1168 B (16B-mult), stride 292 dw ≡ 4 mod 32
#define GT_LD 40    // 32+8 pad: row 80 B (16B-mult); octet XOR-swizzle by (row>>3)&3
#define P_LD  40    // per-wave pbuf rows of 80 B

__global__ __launch_bounds__(512, 2) void mla_sparse_kernel(
    const float* __restrict__ q, const int* __restrict__ topk,
    const float* __restrict__ sink, const unsigned short* __restrict__ kvb,
    float* __restrict__ out)
{
    __shared__ unsigned short g[KT][G_LD];        // gathered [key][d]     37,376 B
    __shared__ unsigned short gt[2][DVAL][GT_LD]; // transposed, dbuf      81,920 B
    __shared__ unsigned short pbuf[8][16][P_LD];  // per-wave P transpose  10,240 B
    __shared__ float bias2[2][KT];                //                          256 B
    // total ~129.8 KB -> 1 block/CU

    const int t    = blockIdx.x;
    const int tid  = threadIdx.x;
    const int wave = tid >> 6;
    const int lane = tid & 63;
    const int quad = lane >> 4;
    const int l16  = lane & 15;
    const int hg    = wave >> 1;   // head group: heads [hg*16, +16)
    const int vhalf = wave & 1;    // vcol half:  [vhalf*256, +256)

    // Q A-frags (x SCALE folded in), 72 VGPRs
    half8 qf[KSTEPS];
    {
        const float* qrow = q + ((size_t)t * NH + (hg * 16 + l16)) * HD;
        #pragma unroll
        for (int ks = 0; ks < KSTEPS; ks++) {
            int d0 = ks * 32 + quad * 8;
            f32x4 a = *(const f32x4*)(qrow + d0);
            f32x4 b = *(const f32x4*)(qrow + d0 + 4);
            half8 h;
            h[0]=(_Float16)(a[0]*SCALE); h[1]=(_Float16)(a[1]*SCALE);
            h[2]=(_Float16)(a[2]*SCALE); h[3]=(_Float16)(a[3]*SCALE);
            h[4]=(_Float16)(b[0]*SCALE); h[5]=(_Float16)(b[1]*SCALE);
            h[6]=(_Float16)(b[2]*SCALE); h[7]=(_Float16)(b[3]*SCALE);
            qf[ks] = h;
        }
    }

    // per-lane online-softmax stats for heads hg*16 + quad*4 + r (r=0..3)
    f32x4 m_run = *(const f32x4*)&sink[hg * 16 + quad * 4];
    f32x4 l_run = {1.f, 1.f, 1.f, 1.f};

    // PV accumulators: 16 vcol tiles of this wave's half (64 VGPRs)
    f32x4 acc[16];
    const f32x4 zero = {0.f, 0.f, 0.f, 0.f};
    #pragma unroll
    for (int nt = 0; nt < 16; nt++) acc[nt] = zero;

    const int* tkrow = topk + (size_t)t * TOPK;
    // staging geometry
    const int kg   = tid >> 7;             // key octet 0..3
    const int xx   = tid & 127;
    const int d0A  = xx * 4;               // value dims
    const int cswz = (xx >> 1) & 3;        // = (row>>3)&3 for rows d0A..d0A+3
    const int keyB = tid >> 4;             // rope key 0..31
    const int dB   = 512 + (tid & 15) * 4;

    us4 v[8], vB;
    int nb;
    auto prefetch = [&](int pit) {
        const int* ip = tkrow + pit * KT + kg * 8;
        i32x4 ra = *(const i32x4*)ip;
        i32x4 rb = *(const i32x4*)(ip + 4);
        unsigned ro[8];
        ro[0] = (unsigned)(ra[0] < 0 ? 0 : ra[0]) * HD;
        ro[1] = (unsigned)(ra[1] < 0 ? 0 : ra[1]) * HD;
        ro[2] = (unsigned)(ra[2] < 0 ? 0 : ra[2]) * HD;
        ro[3] = (unsigned)(ra[3] < 0 ? 0 : ra[3]) * HD;
        ro[4] = (unsigned)(rb[0] < 0 ? 0 : rb[0]) * HD;
        ro[5] = (unsigned)(rb[1] < 0 ? 0 : rb[1]) * HD;
        ro[6] = (unsigned)(rb[2] < 0 ? 0 : rb[2]) * HD;
        ro[7] = (unsigned)(rb[3] < 0 ? 0 : rb[3]) * HD;
        #pragma unroll
        for (int j = 0; j < 8; j++)
            v[j] = *(const us4*)(kvb + (size_t)ro[j] + d0A);
        int ib = tkrow[pit * KT + keyB];
        vB = *(const us4*)(kvb + (size_t)((unsigned)(ib < 0 ? 0 : ib) * HD) + dB);
        nb = tkrow[pit * KT + (tid & (KT - 1))];
    };
    auto stage = [&](int buf) {
        #pragma unroll
        for (int j = 0; j < 8; j++)
            *(us4*)&g[kg * 8 + j][d0A] = v[j];
        #pragma unroll
        for (int dd = 0; dd < 4; dd++) {   // 8-key packs, swizzled b128 writes
            us8 w;
            w[0]=v[0][dd]; w[1]=v[1][dd]; w[2]=v[2][dd]; w[3]=v[3][dd];
            w[4]=v[4][dd]; w[5]=v[5][dd]; w[6]=v[6][dd]; w[7]=v[7][dd];
            *(us8*)&gt[buf][d0A + dd][((kg ^ cswz) & 3) * 8] = w;
        }
        *(us4*)&g[keyB][dB] = vB;
        if (tid < KT) bias2[buf][tid] = (nb < 0) ? -__builtin_inff() : 0.0f;
    };

    prefetch(0);
    stage(0);          // compiler inserts vmcnt waits
    __syncthreads();

    for (int it = 0; it < NITER; it++) {
        const int p = it & 1;
        if (it + 1 < NITER) prefetch(it + 1);   // in flight across S/softmax

        // ---- S: full 32-key row for this wave's 16 heads (2 tiles) ----
        f32x4 s0 = zero, s1 = zero;
        #pragma unroll
        for (int ks = 0; ks < KSTEPS; ks++) {
            half8 b0 = *(const half8*)&g[l16][ks * 32 + quad * 8];
            half8 b1 = *(const half8*)&g[16 + l16][ks * 32 + quad * 8];
            s0 = __builtin_amdgcn_mfma_f32_16x16x32_f16(qf[ks], b0, s0, 0, 0, 0);
            s1 = __builtin_amdgcn_mfma_f32_16x16x32_f16(qf[ks], b1, s1, 0, 0, 0);
        }
        // ---- wave-local online softmax (stats per lane, rows quad*4+r) ----
        {
            float bb0 = bias2[p][l16];
            float bb1 = bias2[p][16 + l16];
            #pragma unroll
            for (int r = 0; r < 4; r++) { s0[r] += bb0; s1[r] += bb1; }
            f32x4 tmx;
            #pragma unroll
            for (int r = 0; r < 4; r++) {
                float x = fmaxf(s0[r], s1[r]);
                x = fmaxf(x, __shfl_xor(x, 1));
                x = fmaxf(x, __shfl_xor(x, 2));
                x = fmaxf(x, __shfl_xor(x, 4));
                x = fmaxf(x, __shfl_xor(x, 8));
                tmx[r] = x;
            }
            f32x4 m_new, alpha, ps;
            #pragma unroll
            for (int r = 0; r < 4; r++) {
                m_new[r] = fmaxf(m_run[r], tmx[r]);   // >= sink: finite
                alpha[r] = __expf(m_run[r] - m_new[r]);
                float p0 = __expf(s0[r] - m_new[r]);
                float p1 = __expf(s1[r] - m_new[r]);
                pbuf[wave][quad * 4 + r][l16]      = f2h(p0);
                pbuf[wave][quad * 4 + r][16 + l16] = f2h(p1);
                float sp = p0 + p1;
                sp += __shfl_xor(sp, 1);
                sp += __shfl_xor(sp, 2);
                sp += __shfl_xor(sp, 4);
                sp += __shfl_xor(sp, 8);
                ps[r] = sp;
            }
            m_run = m_new;
            #pragma unroll
            for (int r = 0; r < 4; r++) l_run[r] = l_run[r] * alpha[r] + ps[r];
            #pragma unroll
            for (int nt = 0; nt < 16; nt++) acc[nt] *= alpha;
        }
        // wave-local P transpose readback (same-wave DS ordering + lgkm wait)
        half8 pa = *(const half8*)&pbuf[wave][l16][quad * 8];

        __syncthreads();   // bar1: all S reads of g done; gt[p] readers not yet started

        if (it + 1 < NITER) stage(1 - p);   // overlaps PV below

        // ---- PV: 16 vcol tiles from gt[p] ----
        #pragma unroll
        for (int nt = 0; nt < 16; nt++) {
            int r = vhalf * 256 + nt * 16 + l16;
            us8 u = *(const us8*)&gt[p][r][((quad ^ (r >> 3)) & 3) * 8];
            half8 vb = __builtin_bit_cast(half8, u);
            acc[nt] = __builtin_amdgcn_mfma_f32_16x16x32_f16(pa, vb, acc[nt], 0, 0, 0);
        }
        __syncthreads();   // bar2: staging writes visible; g free for next S
    }

    // ---- epilogue ----
    f32x4 linv;
    #pragma unroll
    for (int r = 0; r < 4; r++) linv[r] = 1.0f / l_run[r];
    #pragma unroll
    for (int nt = 0; nt < 16; nt++) {
        int vcol = vhalf * 256 + nt * 16 + l16;
        f32x4 res = acc[nt] * linv;
        #pragma unroll
        for (int r = 0; r < 4; r++) {
            int head = hg * 16 + quad * 4 + r;
            out[((size_t)t * NH + head) * DVAL + vcol] = res[r];
        }
    }
}

extern "C" void kernel_launch(void* const* d_in, const int* in_sizes, int n_in,
                              void* d_out, int out_size, void* d_ws, size_t ws_size,
                              hipStream_t stream) {
    const float* q    = (const float*)d_in[0];   // [512,64,576]
    const float* kv   = (const float*)d_in[1];   // [8192,576]
    const int*   topk = (const int*)d_in[2];     // [512,1024]
    const float* sink = (const float*)d_in[3];   // [64]
    float* out = (float*)d_out;                  // [512,64,512]
    unsigned short* kvb = (unsigned short*)d_ws; // fp16 kv cache, 9,437,184 B

    cvt_kv_f16<<<NKV * HD / (256 * 8), 256, 0, stream>>>(kv, kvb);
    mla_sparse_kernel<<<T_TOK, 512, 0, stream>>>(q, topk, sink, kvb, out);
}